// Round 1
// baseline (803.302 us; speedup 1.0000x reference)
//
#include <hip/hip_runtime.h>
#include <hip/hip_bf16.h>
#include <math.h>

#define D_EMBED 512
#define NUM_HEADS 8
#define HEAD_DIM 64
#define D_FF 2048
#define BATCH 2
#define SEQ 4096
#define M_ROWS (BATCH*SEQ)   // 8192

typedef __attribute__((ext_vector_type(8))) short short8;
typedef __attribute__((ext_vector_type(4))) float f32x4;

__device__ inline unsigned short f2b(float f) {
    union { float f; unsigned u; } v; v.f = f;
    unsigned r = v.u + 0x7fffu + ((v.u >> 16) & 1u);
    return (unsigned short)(r >> 16);
}

__device__ inline void gl2lds16(const void* g, void* l) {
    __builtin_amdgcn_global_load_lds(
        (const __attribute__((address_space(1))) unsigned int*)g,
        (__attribute__((address_space(3))) unsigned int*)l, 16, 0, 0);
}

// ---------------------------------------------------------------------------
// GEMM: C[M][N] = A[M][K](bf16) * BT[N][K](bf16)^T + bias
// EPI 0: store bf16; EPI 1: store fp32; EPI 2: GELU(exact) -> bf16
// 128x128 tile, BK=32, 256 threads (4 waves, 2x2), global_load_lds staging.
// ---------------------------------------------------------------------------
template<int EPI>
__global__ __launch_bounds__(256) void gemm_bt(
    const unsigned short* __restrict__ A, const unsigned short* __restrict__ BT,
    const float* __restrict__ bias, void* __restrict__ Cout,
    int M, int N, int K)
{
    __shared__ __align__(16) unsigned short As[128*32];
    __shared__ __align__(16) unsigned short Bs[128*32];
    const int tid  = threadIdx.x;
    const int wave = tid >> 6, lane = tid & 63;
    const int wy = wave >> 1, wx = wave & 1;
    const int quad = lane >> 4, m16 = lane & 15;
    const int row0 = blockIdx.y * 128, n0 = blockIdx.x * 128;

    f32x4 acc[4][4];
#pragma unroll
    for (int i = 0; i < 4; i++)
#pragma unroll
        for (int j = 0; j < 4; j++) acc[i][j] = (f32x4){0.f,0.f,0.f,0.f};

    const int kIters = K >> 5;
    for (int kt = 0; kt < kIters; ++kt) {
        const int k0 = kt << 5;
#pragma unroll
        for (int it = 0; it < 2; ++it) {
            int g  = it*256 + tid;
            int r  = g >> 2, c8 = (g & 3) << 3;
            // LDS dest is wave-uniform base + lane*16 (hardware scatter)
            gl2lds16(A  + (size_t)(row0 + r)*K + k0 + c8, &As[(size_t)(it*256 + wave*64)*8]);
            gl2lds16(BT + (size_t)(n0  + r)*K + k0 + c8, &Bs[(size_t)(it*256 + wave*64)*8]);
        }
        __syncthreads();
        short8 a[4], b[4];
#pragma unroll
        for (int i = 0; i < 4; i++) a[i] = *(const short8*)&As[(wy*64 + i*16 + m16)*32 + quad*8];
#pragma unroll
        for (int j = 0; j < 4; j++) b[j] = *(const short8*)&Bs[(wx*64 + j*16 + m16)*32 + quad*8];
#pragma unroll
        for (int i = 0; i < 4; i++)
#pragma unroll
            for (int j = 0; j < 4; j++)
                acc[i][j] = __builtin_amdgcn_mfma_f32_16x16x32_bf16(a[i], b[j], acc[i][j], 0, 0, 0);
        __syncthreads();
    }

#pragma unroll
    for (int j = 0; j < 4; j++) {
        int col = n0 + wx*64 + j*16 + m16;
        float bj = bias[col];
#pragma unroll
        for (int i = 0; i < 4; i++) {
            int rbase = row0 + wy*64 + i*16 + quad*4;
#pragma unroll
            for (int r = 0; r < 4; r++) {
                float v = acc[i][j][r] + bj;
                size_t idx = (size_t)(rbase + r)*N + col;
                if (EPI == 0) {
                    ((unsigned short*)Cout)[idx] = f2b(v);
                } else if (EPI == 1) {
                    ((float*)Cout)[idx] = v;
                } else {
                    float gv = 0.5f * v * (1.0f + erff(v * 0.70710678118654752f));
                    ((unsigned short*)Cout)[idx] = f2b(gv);
                }
            }
        }
    }
}

// ---------------------------------------------------------------------------
// Flash attention. grid (SEQ/64, B*H), 256 threads. Each wave owns 16 q rows.
// Q,K: bf16 [B*L][512]; VT: bf16 [B*H][64][SEQ]; O(ctx): bf16 [B*L][512].
// ---------------------------------------------------------------------------
__global__ __launch_bounds__(256) void flash_attn(
    const unsigned short* __restrict__ Q, const unsigned short* __restrict__ Kb,
    const unsigned short* __restrict__ VT, const int* __restrict__ mask,
    unsigned short* __restrict__ O)
{
    __shared__ __align__(16) unsigned short Pb[4][16*64];
    const int tid = threadIdx.x, wave = tid >> 6, lane = tid & 63;
    const int quad = lane >> 4, m16 = lane & 15;
    const int bh = blockIdx.y, b = bh >> 3, h = bh & 7;
    const int q0 = blockIdx.x * 64 + wave * 16;

    short8 aq[2];
    {
        const unsigned short* qp = Q + (size_t)(b*SEQ + q0 + m16)*D_EMBED + h*HEAD_DIM + quad*8;
        aq[0] = *(const short8*)(qp);
        aq[1] = *(const short8*)(qp + 32);
    }

    f32x4 accO[4];
#pragma unroll
    for (int dj = 0; dj < 4; dj++) accO[dj] = (f32x4){0.f,0.f,0.f,0.f};
    float mrun[4], lrun[4];
#pragma unroll
    for (int r = 0; r < 4; r++) { mrun[r] = -1e30f; lrun[r] = 0.f; }

    for (int kt = 0; kt < SEQ/64; ++kt) {
        const int key0 = kt * 64;
        int mk[4];
#pragma unroll
        for (int nj = 0; nj < 4; nj++) mk[nj] = mask[b*SEQ + key0 + nj*16 + m16];

        f32x4 sacc[4];
#pragma unroll
        for (int nj = 0; nj < 4; nj++) {
            sacc[nj] = (f32x4){0.f,0.f,0.f,0.f};
            const unsigned short* kp = Kb + (size_t)(b*SEQ + key0 + nj*16 + m16)*D_EMBED + h*HEAD_DIM + quad*8;
            short8 b0 = *(const short8*)kp;
            short8 b1 = *(const short8*)(kp + 32);
            sacc[nj] = __builtin_amdgcn_mfma_f32_16x16x32_bf16(aq[0], b0, sacc[nj], 0, 0, 0);
            sacc[nj] = __builtin_amdgcn_mfma_f32_16x16x32_bf16(aq[1], b1, sacc[nj], 0, 0, 0);
        }

        float s[4][4], mx[4];
#pragma unroll
        for (int r = 0; r < 4; r++) mx[r] = -1e30f;
#pragma unroll
        for (int nj = 0; nj < 4; nj++)
#pragma unroll
            for (int r = 0; r < 4; r++) {
                float v = sacc[nj][r] * 0.125f;          // 1/sqrt(64)
                if (mk[nj] == 0) v = -1e9f;
                s[nj][r] = v;
                mx[r] = fmaxf(mx[r], v);
            }
#pragma unroll
        for (int off = 8; off >= 1; off >>= 1)
#pragma unroll
            for (int r = 0; r < 4; r++)
                mx[r] = fmaxf(mx[r], __shfl_xor(mx[r], off, 64));

        float alpha[4], rs[4];
#pragma unroll
        for (int r = 0; r < 4; r++) {
            float mnew = fmaxf(mrun[r], mx[r]);
            alpha[r] = __expf(mrun[r] - mnew);
            mrun[r] = mnew;
            rs[r] = 0.f;
        }
        float p[4][4];
#pragma unroll
        for (int nj = 0; nj < 4; nj++)
#pragma unroll
            for (int r = 0; r < 4; r++) {
                float pv = __expf(s[nj][r] - mrun[r]);
                p[nj][r] = pv; rs[r] += pv;
            }
#pragma unroll
        for (int off = 8; off >= 1; off >>= 1)
#pragma unroll
            for (int r = 0; r < 4; r++)
                rs[r] += __shfl_xor(rs[r], off, 64);
#pragma unroll
        for (int r = 0; r < 4; r++) lrun[r] = lrun[r]*alpha[r] + rs[r];
#pragma unroll
        for (int dj = 0; dj < 4; dj++)
#pragma unroll
            for (int r = 0; r < 4; r++) accO[dj][r] *= alpha[r];

        // P: C-layout -> LDS -> A-layout (wave-private region)
#pragma unroll
        for (int nj = 0; nj < 4; nj++)
#pragma unroll
            for (int r = 0; r < 4; r++)
                Pb[wave][(quad*4 + r)*64 + nj*16 + m16] = f2b(p[nj][r]);
        __syncthreads();
        short8 aP0 = *(const short8*)&Pb[wave][m16*64 + quad*8];
        short8 aP1 = *(const short8*)&Pb[wave][m16*64 + 32 + quad*8];
        __syncthreads();

#pragma unroll
        for (int dj = 0; dj < 4; dj++) {
            const unsigned short* vp = VT + ((size_t)bh*HEAD_DIM + dj*16 + m16)*SEQ + key0 + quad*8;
            short8 v0 = *(const short8*)vp;
            short8 v1 = *(const short8*)(vp + 32);
            accO[dj] = __builtin_amdgcn_mfma_f32_16x16x32_bf16(aP0, v0, accO[dj], 0, 0, 0);
            accO[dj] = __builtin_amdgcn_mfma_f32_16x16x32_bf16(aP1, v1, accO[dj], 0, 0, 0);
        }
    }

#pragma unroll
    for (int r = 0; r < 4; r++) {
        float rl = 1.0f / lrun[r];
#pragma unroll
        for (int dj = 0; dj < 4; dj++)
            O[(size_t)(b*SEQ + q0 + quad*4 + r)*D_EMBED + h*HEAD_DIM + dj*16 + m16]
                = f2b(accO[dj][r] * rl);
    }
}

// ---------------------------------------------------------------------------
// y = LayerNorm(A + B)*g + be. Writes fp32 (Yf) and optionally bf16 (Yb).
// One wave per row of 512. 4 rows per block.
// ---------------------------------------------------------------------------
__global__ __launch_bounds__(256) void ln_res(
    const float* __restrict__ A, const float* __restrict__ Bv,
    const float* __restrict__ g, const float* __restrict__ be,
    float* __restrict__ Yf, unsigned short* __restrict__ Yb)
{
    const int wave = threadIdx.x >> 6, lane = threadIdx.x & 63;
    const int row = blockIdx.x * 4 + wave;
    const float* ap = A  + (size_t)row*512 + lane*8;
    const float* bp = Bv + (size_t)row*512 + lane*8;
    float v[8]; float s = 0.f;
#pragma unroll
    for (int j = 0; j < 8; j++) { v[j] = ap[j] + bp[j]; s += v[j]; }
#pragma unroll
    for (int off = 32; off >= 1; off >>= 1) s += __shfl_xor(s, off, 64);
    float mu = s * (1.f/512.f);
    float q = 0.f;
#pragma unroll
    for (int j = 0; j < 8; j++) { v[j] -= mu; q += v[j]*v[j]; }
#pragma unroll
    for (int off = 32; off >= 1; off >>= 1) q += __shfl_xor(q, off, 64);
    float rstd = rsqrtf(q * (1.f/512.f) + 1e-5f);
#pragma unroll
    for (int j = 0; j < 8; j++) {
        float y = v[j]*rstd*g[lane*8+j] + be[lane*8+j];
        if (Yf) Yf[(size_t)row*512 + lane*8 + j] = y;
        if (Yb) Yb[(size_t)row*512 + lane*8 + j] = f2b(y);
    }
}

__global__ __launch_bounds__(256) void cvt_f32_bf16(
    const float* __restrict__ X, unsigned short* __restrict__ Y, int n)
{
    int idx = (blockIdx.x * 256 + threadIdx.x) * 4;
    if (idx < n) {
        float4 v = *(const float4*)(X + idx);
        Y[idx+0] = f2b(v.x); Y[idx+1] = f2b(v.y);
        Y[idx+2] = f2b(v.z); Y[idx+3] = f2b(v.w);
    }
}

// W[K][N] fp32 -> WT[N][K] bf16. block (32,8), grid (N/32, K/32)
__global__ void transpose_w(const float* __restrict__ W, unsigned short* __restrict__ WT,
                            int K, int N)
{
    __shared__ float t[32][33];
    int n0 = blockIdx.x*32, k0 = blockIdx.y*32;
    int x = threadIdx.x, y = threadIdx.y;
#pragma unroll
    for (int yy = y; yy < 32; yy += 8) t[yy][x] = W[(size_t)(k0+yy)*N + n0 + x];
    __syncthreads();
#pragma unroll
    for (int yy = y; yy < 32; yy += 8) WT[(size_t)(n0+yy)*K + k0 + x] = f2b(t[x][yy]);
}

// V bf16 [B*L][512] -> VT bf16 [B*H][64][SEQ]. grid (SEQ/32, 2, 16), block (32,8)
__global__ void transpose_v(const unsigned short* __restrict__ V, unsigned short* __restrict__ VT)
{
    __shared__ unsigned short t[32][33];
    int bh = blockIdx.z, b = bh >> 3, h = bh & 7;
    int l0 = blockIdx.x*32, d0 = blockIdx.y*32;
    int x = threadIdx.x, y = threadIdx.y;
#pragma unroll
    for (int yy = y; yy < 32; yy += 8) t[yy][x] = V[(size_t)(b*SEQ + l0+yy)*512 + h*64 + d0 + x];
    __syncthreads();
#pragma unroll
    for (int yy = y; yy < 32; yy += 8) VT[((size_t)bh*64 + d0+yy)*SEQ + l0 + x] = t[x][yy];
}

extern "C" void kernel_launch(void* const* d_in, const int* in_sizes, int n_in,
                              void* d_out, int out_size, void* d_ws, size_t ws_size,
                              hipStream_t stream)
{
    const float* x    = (const float*)d_in[0];
    const int*   mask = (const int*)  d_in[1];
    const float* Wq = (const float*)d_in[2];  const float* bq = (const float*)d_in[3];
    const float* Wk = (const float*)d_in[4];  const float* bk = (const float*)d_in[5];
    const float* Wv = (const float*)d_in[6];  const float* bv = (const float*)d_in[7];
    const float* Wo = (const float*)d_in[8];  const float* bo = (const float*)d_in[9];
    const float* ln1g = (const float*)d_in[10]; const float* ln1b = (const float*)d_in[11];
    const float* ln2g = (const float*)d_in[12]; const float* ln2b = (const float*)d_in[13];
    const float* W1 = (const float*)d_in[14]; const float* b1 = (const float*)d_in[15];
    const float* W2 = (const float*)d_in[16]; const float* b2 = (const float*)d_in[17];
    float* out = (float*)d_out;

    char* ws = (char*)d_ws;
    const size_t MB = 1024*1024;
    unsigned short* xb  = (unsigned short*)(ws + 0);          // 8 MB
    unsigned short* WqT = (unsigned short*)(ws + 8*MB);
    unsigned short* WkT = (unsigned short*)(ws + 8*MB + 512*1024);
    unsigned short* WvT = (unsigned short*)(ws + 9*MB);
    unsigned short* WoT = (unsigned short*)(ws + 9*MB + 512*1024);
    unsigned short* W1T = (unsigned short*)(ws + 10*MB);      // 2 MB
    unsigned short* W2T = (unsigned short*)(ws + 12*MB);      // 2 MB
    unsigned short* Qb  = (unsigned short*)(ws + 14*MB);      // 8 MB
    unsigned short* Kb  = (unsigned short*)(ws + 22*MB);      // 8 MB
    unsigned short* Vb  = (unsigned short*)(ws + 30*MB);      // 8 MB
    unsigned short* VTb = (unsigned short*)(ws + 38*MB);      // 8 MB
    unsigned short* ctx = (unsigned short*)(ws + 46*MB);      // 8 MB
    float*          atf = (float*)(ws + 54*MB);               // 16 MB
    float*          hf  = (float*)(ws + 70*MB);               // 16 MB
    unsigned short* hb  = (unsigned short*)(ws + 86*MB);      // 8 MB  (peak 94 MB)
    unsigned short* Gb  = (unsigned short*)(ws + 14*MB);      // 32 MB, overlays dead Q/K/V/VT
    float*          ff  = (float*)(ws + 46*MB);               // 16 MB, overlays dead ctx/atf

    dim3 tb(32, 8);
    cvt_f32_bf16<<<4096, 256, 0, stream>>>(x, xb, M_ROWS*D_EMBED);
    transpose_w<<<dim3(16,16), tb, 0, stream>>>(Wq, WqT, 512, 512);
    transpose_w<<<dim3(16,16), tb, 0, stream>>>(Wk, WkT, 512, 512);
    transpose_w<<<dim3(16,16), tb, 0, stream>>>(Wv, WvT, 512, 512);
    transpose_w<<<dim3(16,16), tb, 0, stream>>>(Wo, WoT, 512, 512);
    transpose_w<<<dim3(64,16), tb, 0, stream>>>(W1, W1T, 512, 2048);
    transpose_w<<<dim3(16,64), tb, 0, stream>>>(W2, W2T, 2048, 512);

    gemm_bt<0><<<dim3(4,64), 256, 0, stream>>>(xb, WqT, bq, Qb, M_ROWS, 512, 512);
    gemm_bt<0><<<dim3(4,64), 256, 0, stream>>>(xb, WkT, bk, Kb, M_ROWS, 512, 512);
    gemm_bt<0><<<dim3(4,64), 256, 0, stream>>>(xb, WvT, bv, Vb, M_ROWS, 512, 512);

    transpose_v<<<dim3(SEQ/32, 2, 16), tb, 0, stream>>>(Vb, VTb);
    flash_attn<<<dim3(SEQ/64, 16), 256, 0, stream>>>(Qb, Kb, VTb, mask, ctx);

    gemm_bt<1><<<dim3(4,64), 256, 0, stream>>>(ctx, WoT, bo, atf, M_ROWS, 512, 512);
    ln_res<<<M_ROWS/4, 256, 0, stream>>>(x, atf, ln1g, ln1b, hf, hb);

    gemm_bt<2><<<dim3(16,64), 256, 0, stream>>>(hb, W1T, b1, Gb, M_ROWS, D_FF, 512);
    gemm_bt<1><<<dim3(4,64), 256, 0, stream>>>(Gb, W2T, b2, ff, M_ROWS, 512, D_FF);
    ln_res<<<M_ROWS/4, 256, 0, stream>>>(hf, ff, ln2g, ln2b, out, (unsigned short*)nullptr);
}